// Round 9
// baseline (1021.166 us; speedup 1.0000x reference)
//
#include <hip/hip_runtime.h>
#include <hip/hip_fp16.h>

typedef __attribute__((ext_vector_type(8))) _Float16 half8;
typedef __attribute__((ext_vector_type(4))) _Float16 half4;
typedef __attribute__((ext_vector_type(4))) float float4a;

// ---- workspace layout (elements of _Float16) ----
#define WT_PLANE 3145728
#define WS_FC    6291456
#define WS_FC_LO 6307840
#define WS_QKV   6324224           // QKV planes: [bl][5][16384]
#define QKV_STRIDE 81920
#define OQH 0
#define OQL 16384
#define OKH 32768
#define OKL 49152
#define OVT 65536                  // V^T [a=64][m=256]
// total ws = (6324224 + 1024*81920)*2B ≈ 180.4 MB

// ---- kernel A LDS (96 KB, 1 block/CU, 16 waves = 4/EU) ----
#define A_XH 0
#define A_XL 32768
#define A_VT 65536
#define LDS_A 98304

// ---- kernel B LDS (64 KB, 2 blocks/CU, 16 waves = 4/EU) ----
#define B_PT   0                   // P f16 [64][256] swz512 (32 KB)
#define B_PVH  32768               // PV hi f16 [64][64] swz128 (8 KB)
#define B_PVL  40960
#define B_RED1 49152               // [64][2] f32
#define B_RED2 49664
#define B_FCT  0                   // f32 [64][256] overlay (64 KB)
#define LDS_B 65536

__device__ __forceinline__ int swz128(int r, int c) {
    return (r << 7) + ((((c >> 3) ^ r) & 7) << 4) + ((c & 7) << 1);
}
__device__ __forceinline__ int swz512(int r, int c) {
    return (r << 9) + (((((c >> 3) ^ (r & 7))) & 31) << 4) + ((c & 7) << 1);
}

// LDS-only barrier: does NOT drain vmcnt (global loads/stores stay in flight).
__device__ __forceinline__ void lds_barrier() {
    __builtin_amdgcn_sched_barrier(0);
    asm volatile("s_waitcnt lgkmcnt(0)" ::: "memory");
    __builtin_amdgcn_s_barrier();
    __builtin_amdgcn_sched_barrier(0);
}

// ---------------- prep: W -> WT (f16 hi/lo, transposed), fcw -> f16 hi/lo ----
extern "C" __global__ void __launch_bounds__(256)
va_prep(const float* __restrict__ Wq, const float* __restrict__ Wk,
        const float* __restrict__ Wv, const float* __restrict__ fcw,
        _Float16* __restrict__ ws)
{
    __shared__ float tile[16384];
    const int t = (int)threadIdx.x;
    const int blk = (int)blockIdx.x;
    if (blk < 192) {
        const int mat = blk >> 6, l = blk & 63;
        const float* W = (mat == 0 ? Wq : mat == 1 ? Wk : Wv) + l * 16384;
        #pragma unroll
        for (int i = 0; i < 16; ++i) {
            const int f = (i * 256 + t) * 4;
            *(float4a*)&tile[f] = *(const float4a*)(W + f);
        }
        __syncthreads();
        const int a = t & 63, cgp = t >> 6;
        const int obase = ((mat * 64 + l) * 64 + a) * 256;
        #pragma unroll
        for (int p = 0; p < 8; ++p) {
            const int c0 = cgp * 64 + p * 8;
            half8 hh, hl;
            #pragma unroll
            for (int q = 0; q < 8; ++q) {
                const float v = tile[(c0 + q) * 64 + a];
                const _Float16 h = (_Float16)v;
                hh[q] = h;
                hl[q] = (_Float16)(v - (float)h);
            }
            *(half8*)(ws + obase + c0) = hh;
            *(half8*)(ws + WT_PLANE + obase + c0) = hl;
        }
    } else {
        #pragma unroll
        for (int i = 0; i < 16; ++i) {
            const int f = (i * 256 + t) * 4;
            const float4a v = *(const float4a*)(fcw + f);
            half4 hh, hl;
            #pragma unroll
            for (int q = 0; q < 4; ++q) {
                const _Float16 h = (_Float16)v[q];
                hh[q] = h;
                hl[q] = (_Float16)(v[q] - (float)h);
            }
            *(half4*)(ws + WS_FC + f) = hh;
            *(half4*)(ws + WS_FC_LO + f) = hl;
        }
    }
}

// ---------------- kernel A: QKV projection -> ws f16 planes ----------------
extern "C" __global__ void
__launch_bounds__(1024)
__attribute__((amdgpu_waves_per_eu(4, 4)))
va_proj(const float* __restrict__ Y,
        const float* __restrict__ bq, const float* __restrict__ bk,
        const float* __restrict__ bv,
        _Float16* __restrict__ ws)
{
    extern __shared__ char smem[];
    const int tid  = (int)threadIdx.x;
    const int w    = tid >> 6;    // 0..15
    const int lane = tid & 63;
    const int l15  = lane & 15;
    const int kg   = lane >> 4;

    const int i0 = (int)blockIdx.x;
    const int x  = i0 & 7, q0 = i0 >> 3;
    const int b  = q0 >> 3;
    const int l  = ((q0 & 7) << 3) | x;

    const float* __restrict__ Yb =
        Y + (size_t)b * (256u * 16384u) + (size_t)l * 256u;

    const int rg = w >> 2;   // rows rg*64..+63
    const int cg = w & 3;    // a-cols cg*16..+15 of each matrix

    float4a acc[4][3];
    #pragma unroll
    for (int rt = 0; rt < 4; ++rt)
        #pragma unroll
        for (int ct = 0; ct < 3; ++ct) acc[rt][ct] = (float4a)0.0f;

    const int srow = tid >> 2;
    const int scol = (tid & 3) * 16;
    const float* xsrc = Yb + (size_t)srow * 16384 + scol;

    auto wload = [&](int kt, int ks, half8* bh, half8* bl) {
        #pragma unroll
        for (int ct = 0; ct < 3; ++ct) {
            const int widx = ((ct * 64 + l) * 64 + cg * 16 + l15) * 256
                             + kt * 64 + ks * 32 + kg * 8;
            bh[ct] = *(const half8*)(ws + widx);
            bl[ct] = *(const half8*)(ws + WT_PLANE + widx);
        }
    };

    float4a xr[4];
    #pragma unroll
    for (int p = 0; p < 4; ++p) xr[p] = *(const float4a*)(xsrc + p * 4);

    #pragma unroll 1
    for (int kt = 0; kt < 4; ++kt) {
        #pragma unroll
        for (int p = 0; p < 4; ++p) {
            const int c = scol + p * 4;
            half4 hh, hl;
            #pragma unroll
            for (int q = 0; q < 4; ++q) {
                const float v = xr[p][q];
                const _Float16 h = (_Float16)v;
                hh[q] = h;
                hl[q] = (_Float16)(v - (float)h);
            }
            *(half4*)(smem + A_XH + swz128(srow, c)) = hh;
            *(half4*)(smem + A_XL + swz128(srow, c)) = hl;
        }
        if (kt < 3) {
            #pragma unroll
            for (int p = 0; p < 4; ++p)
                xr[p] = *(const float4a*)(xsrc + (kt + 1) * 64 + p * 4);
        }
        half8 bh0[3], bl0[3];
        wload(kt, 0, bh0, bl0);
        lds_barrier();
        #pragma unroll
        for (int rt = 0; rt < 4; ++rt) {
            const int row = rg * 64 + rt * 16 + l15;
            const half8 ah = *(const half8*)(smem + A_XH + swz128(row, kg * 8));
            const half8 al = *(const half8*)(smem + A_XL + swz128(row, kg * 8));
            #pragma unroll
            for (int ct = 0; ct < 3; ++ct) {
                acc[rt][ct] = __builtin_amdgcn_mfma_f32_16x16x32_f16(ah, bh0[ct], acc[rt][ct], 0, 0, 0);
                acc[rt][ct] = __builtin_amdgcn_mfma_f32_16x16x32_f16(ah, bl0[ct], acc[rt][ct], 0, 0, 0);
                acc[rt][ct] = __builtin_amdgcn_mfma_f32_16x16x32_f16(al, bh0[ct], acc[rt][ct], 0, 0, 0);
            }
        }
        half8 bh1[3], bl1[3];
        wload(kt, 1, bh1, bl1);
        #pragma unroll
        for (int rt = 0; rt < 4; ++rt) {
            const int row = rg * 64 + rt * 16 + l15;
            const half8 ah = *(const half8*)(smem + A_XH + swz128(row, 32 + kg * 8));
            const half8 al = *(const half8*)(smem + A_XL + swz128(row, 32 + kg * 8));
            #pragma unroll
            for (int ct = 0; ct < 3; ++ct) {
                acc[rt][ct] = __builtin_amdgcn_mfma_f32_16x16x32_f16(ah, bh1[ct], acc[rt][ct], 0, 0, 0);
                acc[rt][ct] = __builtin_amdgcn_mfma_f32_16x16x32_f16(ah, bl1[ct], acc[rt][ct], 0, 0, 0);
                acc[rt][ct] = __builtin_amdgcn_mfma_f32_16x16x32_f16(al, bh1[ct], acc[rt][ct], 0, 0, 0);
            }
        }
        lds_barrier();
    }

    // epilogue: bias; Q/K hi/lo scalar stores (L2 write-combines 32B segments);
    // V through LDS for a coalesced V^T store.
    const size_t qb = (size_t)WS_QKV + (size_t)((b << 6) | l) * QKV_STRIDE;
    _Float16* __restrict__ pQh = ws + qb + OQH;
    _Float16* __restrict__ pQl = ws + qb + OQL;
    _Float16* __restrict__ pKh = ws + qb + OKH;
    _Float16* __restrict__ pKl = ws + qb + OKL;
    _Float16* __restrict__ pVT = ws + qb + OVT;
    {
        const int a = cg * 16 + l15;
        const float biq = bq[a], bik = bk[a], biv = bv[a];
        #pragma unroll
        for (int rt = 0; rt < 4; ++rt) {
            #pragma unroll
            for (int jj = 0; jj < 4; ++jj) {
                const int row = rg * 64 + rt * 16 + kg * 4 + jj;
                const float qv = acc[rt][0][jj] + biq;
                const _Float16 qh = (_Float16)qv;
                pQh[row * 64 + a] = qh;
                pQl[row * 64 + a] = (_Float16)(qv - (float)qh);
                const float kv = acc[rt][1][jj] + bik;
                const _Float16 kh = (_Float16)kv;
                pKh[row * 64 + a] = kh;
                pKl[row * 64 + a] = (_Float16)(kv - (float)kh);
            }
            const int m0 = rg * 64 + rt * 16 + kg * 4;
            half4 vh;
            #pragma unroll
            for (int jj = 0; jj < 4; ++jj)
                vh[jj] = (_Float16)(acc[rt][2][jj] + biv);
            *(half4*)(smem + A_VT + swz512(a, m0)) = vh;
        }
    }
    lds_barrier();
    {
        const int e0 = tid * 16;
        const int va = e0 >> 8, vm = e0 & 255;
        *(half8*)(pVT + e0) = *(const half8*)(smem + A_VT + swz512(va, vm));
        *(half8*)(pVT + e0 + 8) = *(const half8*)(smem + A_VT + swz512(va, vm + 8));
    }
}

// ---------------- kernel B: attention + fc + residual ----------------
// LDS 64 KB -> 2 blocks/CU -> 4 waves/EU. Q/K/V fragments read directly
// from ws (L2/L3-hot, 16x reuse) -- no K/V LDS staging, no S-phase barrier.
extern "C" __global__ void
__launch_bounds__(512)
__attribute__((amdgpu_waves_per_eu(4, 4)))
va_attn(const float* __restrict__ Y,
        const float* __restrict__ gama, const float* __restrict__ fcb,
        const _Float16* __restrict__ ws,
        float* __restrict__ out)
{
    extern __shared__ char smem[];
    const int tid  = (int)threadIdx.x;
    const int w    = tid >> 6;    // 0..7
    const int lane = tid & 63;
    const int l15  = lane & 15;
    const int kg   = lane >> 4;

    const int i0 = (int)blockIdx.x;
    const int x  = i0 & 7, q0 = i0 >> 3;
    const int b  = q0 >> 3;
    const int l  = ((q0 & 7) << 3) | x;

    const size_t base = (size_t)b * (256u * 16384u) + (size_t)l * 256u;
    const float* __restrict__ Yb = Y + base;
    float* __restrict__ Ob = out + base;

    const size_t qb = (size_t)WS_QKV + (size_t)((b << 6) | l) * QKV_STRIDE;
    const _Float16* __restrict__ pQh = ws + qb + OQH;
    const _Float16* __restrict__ pQl = ws + qb + OQL;
    const _Float16* __restrict__ pKh = ws + qb + OKH;
    const _Float16* __restrict__ pKl = ws + qb + OKL;
    const _Float16* __restrict__ pVT = ws + qb + OVT;

    const int rt_s = w & 3;    // chunk-local row-tile
    const int mq   = w >> 2;   // S: m-half
    const int ah2  = w >> 2;   // PV: a-half
    const int cgf  = w >> 2;   // fc: col-half

    const float gv = gama[0];
    const float4a fcb4 = *(const float4a*)&fcb[lane * 4];
    float* red1 = (float*)(smem + B_RED1);
    float* red2 = (float*)(smem + B_RED2);
    float* FCt  = (float*)(smem + B_FCT);

    #pragma unroll 1
    for (int ci = 0; ci < 4; ++ci) {
        // ---- 1. S = Q K^T (3-term split-f16 MFMA), operands from global ----
        float4a sacc[8];
        #pragma unroll
        for (int mt = 0; mt < 8; ++mt) sacc[mt] = (float4a)0.0f;
        const int arow = ci * 64 + rt_s * 16 + l15;
        #pragma unroll
        for (int ks = 0; ks < 2; ++ks) {
            const int a0 = ks * 32 + kg * 8;
            const half8 ah = *(const half8*)(pQh + arow * 64 + a0);
            const half8 al = *(const half8*)(pQl + arow * 64 + a0);
            #pragma unroll
            for (int mt = 0; mt < 8; ++mt) {
                const int mcol = mq * 128 + mt * 16 + l15;
                const half8 bh = *(const half8*)(pKh + mcol * 64 + a0);
                const half8 bl = *(const half8*)(pKl + mcol * 64 + a0);
                sacc[mt] = __builtin_amdgcn_mfma_f32_16x16x32_f16(ah, bh, sacc[mt], 0, 0, 0);
                sacc[mt] = __builtin_amdgcn_mfma_f32_16x16x32_f16(ah, bl, sacc[mt], 0, 0, 0);
                sacc[mt] = __builtin_amdgcn_mfma_f32_16x16x32_f16(al, bh, sacc[mt], 0, 0, 0);
            }
        }

        // ---- 2. softmax over m (merged reduction, [64][2] slots) ----
        float mloc[4];
        #pragma unroll
        for (int jj = 0; jj < 4; ++jj) {
            float m0 = sacc[0][jj];
            #pragma unroll
            for (int mt = 1; mt < 8; ++mt) m0 = fmaxf(m0, sacc[mt][jj]);
            m0 = fmaxf(m0, __shfl_xor(m0, 1));
            m0 = fmaxf(m0, __shfl_xor(m0, 2));
            m0 = fmaxf(m0, __shfl_xor(m0, 4));
            m0 = fmaxf(m0, __shfl_xor(m0, 8));
            mloc[jj] = m0;
        }
        #pragma unroll
        for (int mt = 0; mt < 8; ++mt)
            #pragma unroll
            for (int jj = 0; jj < 4; ++jj)
                sacc[mt][jj] = __expf(sacc[mt][jj] - mloc[jj]);
        #pragma unroll
        for (int jj = 0; jj < 4; ++jj) {
            float s0 = 0.0f;
            #pragma unroll
            for (int mt = 0; mt < 8; ++mt) s0 += sacc[mt][jj];
            s0 += __shfl_xor(s0, 1);
            s0 += __shfl_xor(s0, 2);
            s0 += __shfl_xor(s0, 4);
            s0 += __shfl_xor(s0, 8);
            if (l15 == 0) {
                const int rloc = rt_s * 16 + kg * 4 + jj;
                red1[rloc * 2 + mq] = mloc[jj];
                red2[rloc * 2 + mq] = s0;
            }
        }
        lds_barrier();
        #pragma unroll
        for (int jj = 0; jj < 4; ++jj) {
            const int rloc = rt_s * 16 + kg * 4 + jj;
            const float rm0 = red1[rloc * 2], rm1 = red1[rloc * 2 + 1];
            const float rs0 = red2[rloc * 2], rs1 = red2[rloc * 2 + 1];
            const float gmax = fmaxf(rm0, rm1);
            const float total = rs0 * __expf(rm0 - gmax) + rs1 * __expf(rm1 - gmax);
            const float fac = __expf(mloc[jj] - gmax) / total;
            #pragma unroll
            for (int mt = 0; mt < 8; ++mt) {
                const int mcol = mq * 128 + mt * 16 + l15;
                *(_Float16*)(smem + B_PT + swz512(rloc, mcol)) =
                    (_Float16)(sacc[mt][jj] * fac);
            }
        }
        lds_barrier();

        // ---- 3. PV = P * V (P from LDS, V^T from global) ----
        float4a pacc[2];
        pacc[0] = (float4a)0.0f; pacc[1] = (float4a)0.0f;
        #pragma unroll
        for (int ks = 0; ks < 8; ++ks) {
            const int mk = ks * 32 + kg * 8;
            const half8 pa = *(const half8*)(smem + B_PT + swz512(rt_s * 16 + l15, mk));
            #pragma unroll
            for (int i = 0; i < 2; ++i) {
                const int av = (ah2 * 2 + i) * 16 + l15;
                const half8 vb = *(const half8*)(pVT + av * 256 + mk);
                pacc[i] = __builtin_amdgcn_mfma_f32_16x16x32_f16(pa, vb, pacc[i], 0, 0, 0);
            }
        }
        #pragma unroll
        for (int i = 0; i < 2; ++i)
            #pragma unroll
            for (int jj = 0; jj < 4; ++jj) {
                const int rloc = rt_s * 16 + kg * 4 + jj;
                const int colp = (ah2 * 2 + i) * 16 + l15;
                const float pv = pacc[i][jj];
                const _Float16 ph = (_Float16)pv;
                *(_Float16*)(smem + B_PVH + swz128(rloc, colp)) = ph;
                *(_Float16*)(smem + B_PVL + swz128(rloc, colp)) = (_Float16)(pv - (float)ph);
            }
        lds_barrier();

        // ---- 4. fc via MFMA (3-term; weights from ws, L2-hot) ----
        float4a facc[8];
        #pragma unroll
        for (int i = 0; i < 8; ++i) facc[i] = (float4a)0.0f;
        #pragma unroll
        for (int ks = 0; ks < 2; ++ks) {
            const int aoff = ks * 32 + kg * 8;
            const half8 ah = *(const half8*)(smem + B_PVH + swz128(rt_s * 16 + l15, aoff));
            const half8 al = *(const half8*)(smem + B_PVL + swz128(rt_s * 16 + l15, aoff));
            #pragma unroll
            for (int i = 0; i < 8; ++i) {
                const int cc = cgf * 128 + i * 16 + l15;
                const half8 bfh = *(const half8*)(ws + WS_FC + cc * 64 + aoff);
                const half8 bfl = *(const half8*)(ws + WS_FC_LO + cc * 64 + aoff);
                facc[i] = __builtin_amdgcn_mfma_f32_16x16x32_f16(ah, bfh, facc[i], 0, 0, 0);
                facc[i] = __builtin_amdgcn_mfma_f32_16x16x32_f16(al, bfh, facc[i], 0, 0, 0);
                facc[i] = __builtin_amdgcn_mfma_f32_16x16x32_f16(ah, bfl, facc[i], 0, 0, 0);
            }
        }
        // prefetch residual rows while fc finishes (stays in flight across barrier)
        float4a yres[8];
        #pragma unroll
        for (int rr = 0; rr < 8; ++rr)
            yres[rr] = *(const float4a*)(Yb + (size_t)(ci * 64 + w * 8 + rr) * 16384 + lane * 4);
        lds_barrier();   // PVH/PVL reads complete before FCt overwrites region

        // ---- 5. FCt exchange (f32) -> coalesced residual store ----
        #pragma unroll
        for (int i = 0; i < 8; ++i)
            #pragma unroll
            for (int jj = 0; jj < 4; ++jj)
                FCt[(rt_s * 16 + kg * 4 + jj) * 256 + cgf * 128 + i * 16 + l15] = facc[i][jj];
        lds_barrier();
        #pragma unroll
        for (int rr = 0; rr < 8; ++rr) {
            const float4a f4 = *(const float4a*)&FCt[(w * 8 + rr) * 256 + lane * 4];
            float4a r4;
            #pragma unroll
            for (int c = 0; c < 4; ++c)
                r4[c] = yres[rr][c] + gv * (f4[c] + fcb4[c]);
            *(float4a*)(Ob + (size_t)(ci * 64 + w * 8 + rr) * 16384 + lane * 4) = r4;
        }
        lds_barrier();   // FCt reads done before next chunk's LDS writes
    }
}

extern "C" void kernel_launch(void* const* d_in, const int* in_sizes, int n_in,
                              void* d_out, int out_size, void* d_ws, size_t ws_size,
                              hipStream_t stream) {
    (void)in_sizes; (void)n_in; (void)ws_size; (void)out_size;
    const float* Y    = (const float*)d_in[0];
    const float* Wq   = (const float*)d_in[1];
    const float* Wk   = (const float*)d_in[2];
    const float* Wv   = (const float*)d_in[3];
    const float* bq   = (const float*)d_in[4];
    const float* bk   = (const float*)d_in[5];
    const float* bv   = (const float*)d_in[6];
    const float* gama = (const float*)d_in[7];
    const float* fcw  = (const float*)d_in[8];
    const float* fcb  = (const float*)d_in[9];
    float* outp = (float*)d_out;
    _Float16* ws = (_Float16*)d_ws;

    (void)hipFuncSetAttribute((const void*)va_proj,
                              hipFuncAttributeMaxDynamicSharedMemorySize, LDS_A);
    (void)hipFuncSetAttribute((const void*)va_attn,
                              hipFuncAttributeMaxDynamicSharedMemorySize, LDS_B);

    va_prep<<<dim3(193), dim3(256), 0, stream>>>(Wq, Wk, Wv, fcw, ws);
    va_proj<<<dim3(1024), dim3(1024), LDS_A, stream>>>(Y, bq, bk, bv, ws);
    va_attn<<<dim3(1024), dim3(512), LDS_B, stream>>>(Y, gama, fcb, ws, outp);
}

// Round 10
// 472.805 us; speedup vs baseline: 2.1598x; 2.1598x over previous
//
#include <hip/hip_runtime.h>
#include <hip/hip_fp16.h>

typedef __attribute__((ext_vector_type(8))) _Float16 half8;
typedef __attribute__((ext_vector_type(4))) _Float16 half4;
typedef __attribute__((ext_vector_type(4))) float float4a;

// ---- workspace layout (elements of _Float16) ----
#define WT_PLANE 3145728
#define WS_FC    6291456
#define WS_FC_LO 6307840

// ---- LDS layout (bytes), total 163840 ----
#define OFF_KH   0
#define OFF_KL   32768
#define OFF_VST  65536
#define OFF_XH   98304
#define OFF_XL   131072
#define OFF_QTH  98304
#define OFF_QTL  106496
#define OFF_PT   114688
#define OFF_PVH  147456
#define OFF_PVL  155648
#define OFF_RED1 147456
#define OFF_RED2 148480
#define LDS_BYTES 163840

__device__ __forceinline__ int swz128(int r, int c) {
    return (r << 7) + ((((c >> 3) ^ r) & 7) << 4) + ((c & 7) << 1);
}
__device__ __forceinline__ int swz512(int r, int c) {
    return (r << 9) + (((((c >> 3) ^ (r & 7))) & 31) << 4) + ((c & 7) << 1);
}

// LDS-only barrier: does NOT drain vmcnt (global loads/stores stay in flight).
__device__ __forceinline__ void lds_barrier() {
    __builtin_amdgcn_sched_barrier(0);
    asm volatile("s_waitcnt lgkmcnt(0)" ::: "memory");
    __builtin_amdgcn_s_barrier();
    __builtin_amdgcn_sched_barrier(0);
}

// ---------------- prep: W -> WT (f16 hi/lo, transposed), fcw -> f16 hi/lo ----
extern "C" __global__ void __launch_bounds__(256)
va_prep(const float* __restrict__ Wq, const float* __restrict__ Wk,
        const float* __restrict__ Wv, const float* __restrict__ fcw,
        _Float16* __restrict__ ws)
{
    __shared__ float tile[16384];
    const int t = (int)threadIdx.x;
    const int blk = (int)blockIdx.x;
    if (blk < 192) {
        const int mat = blk >> 6, l = blk & 63;
        const float* W = (mat == 0 ? Wq : mat == 1 ? Wk : Wv) + l * 16384;
        #pragma unroll
        for (int i = 0; i < 16; ++i) {
            const int f = (i * 256 + t) * 4;
            *(float4a*)&tile[f] = *(const float4a*)(W + f);
        }
        __syncthreads();
        const int a = t & 63, cgp = t >> 6;
        const int obase = ((mat * 64 + l) * 64 + a) * 256;
        #pragma unroll
        for (int p = 0; p < 8; ++p) {
            const int c0 = cgp * 64 + p * 8;
            half8 hh, hl;
            #pragma unroll
            for (int q = 0; q < 8; ++q) {
                const float v = tile[(c0 + q) * 64 + a];
                const _Float16 h = (_Float16)v;
                hh[q] = h;
                hl[q] = (_Float16)(v - (float)h);
            }
            *(half8*)(ws + obase + c0) = hh;
            *(half8*)(ws + WT_PLANE + obase + c0) = hl;
        }
    } else {
        #pragma unroll
        for (int i = 0; i < 16; ++i) {
            const int f = (i * 256 + t) * 4;
            const float4a v = *(const float4a*)(fcw + f);
            half4 hh, hl;
            #pragma unroll
            for (int q = 0; q < 4; ++q) {
                const _Float16 h = (_Float16)v[q];
                hh[q] = h;
                hl[q] = (_Float16)(v[q] - (float)h);
            }
            *(half4*)(ws + WS_FC + f) = hh;
            *(half4*)(ws + WS_FC_LO + f) = hl;
        }
    }
}

// ---------------- main fused kernel ----------------
// r10: r8 structure (512 thr, 256-reg budget, no spill) with the phase-B
// barrier chain cut from 7 to 4 per chunk: fc result + gated residual are
// stored DIRECTLY from MFMA C-layout (64B segments), Y loaded in the same
// scattered pattern and issued early. FCt exchange + 3 barriers removed.
extern "C" __global__ void
__launch_bounds__(512)
__attribute__((amdgpu_waves_per_eu(2, 2)))
va_fused(const float* __restrict__ Y,
         const float* __restrict__ bq, const float* __restrict__ bk,
         const float* __restrict__ bv,
         const float* __restrict__ gama, const float* __restrict__ fcb,
         const _Float16* __restrict__ ws,
         float* __restrict__ out)
{
    extern __shared__ char smem[];
    const int tid  = (int)threadIdx.x;
    const int w    = tid >> 6;    // wave 0..7
    const int lane = tid & 63;
    const int l15  = lane & 15;
    const int kg   = lane >> 4;

    // XCD-aware swizzle (bijective): each XCD sees a stable set of 8 l's.
    const int i0 = (int)blockIdx.x;
    const int x  = i0 & 7, q0 = i0 >> 3;
    const int b  = q0 >> 3;
    const int l  = ((q0 & 7) << 3) | x;

    const size_t base = (size_t)b * (256u * 16384u) + (size_t)l * 256u;
    const float* __restrict__ Yb = Y + base;
    float* __restrict__ Ob = out + base;

    const int rg = w >> 2;   // phase A: row-group (rows rg*128..+127)
    const int cg = w & 3;    // phase A: a-subgroup

    // ============ Phase A: QKV = X * W via split-f16 MFMA ============
    float4a acc[8][3];
    #pragma unroll
    for (int rt = 0; rt < 8; ++rt)
        #pragma unroll
        for (int ct = 0; ct < 3; ++ct) acc[rt][ct] = (float4a)0.0f;

    const int srow = tid >> 1;          // 0..255
    const int scol = (tid & 1) * 32;
    const float* xsrc = Yb + (size_t)srow * 16384 + scol;

    auto wload = [&](int kt, int ks, half8* bh, half8* bl) {
        #pragma unroll
        for (int ct = 0; ct < 3; ++ct) {
            const int widx = ((ct * 64 + l) * 64 + cg * 16 + l15) * 256
                             + kt * 64 + ks * 32 + kg * 8;
            bh[ct] = *(const half8*)(ws + widx);
            bl[ct] = *(const half8*)(ws + WT_PLANE + widx);
        }
    };

    float4a xr[8];
    #pragma unroll
    for (int p = 0; p < 8; ++p) xr[p] = *(const float4a*)(xsrc + p * 4);

    #pragma unroll 1
    for (int kt = 0; kt < 4; ++kt) {
        #pragma unroll
        for (int p = 0; p < 8; ++p) {
            const int c = scol + p * 4;
            half4 hh, hl;
            #pragma unroll
            for (int q = 0; q < 4; ++q) {
                const float v = xr[p][q];
                const _Float16 h = (_Float16)v;
                hh[q] = h;
                hl[q] = (_Float16)(v - (float)h);
            }
            *(half4*)(smem + OFF_XH + swz128(srow, c)) = hh;
            *(half4*)(smem + OFF_XL + swz128(srow, c)) = hl;
        }
        if (kt < 3) {
            #pragma unroll
            for (int p = 0; p < 8; ++p)
                xr[p] = *(const float4a*)(xsrc + (kt + 1) * 64 + p * 4);
        }
        half8 bh0[3], bl0[3];
        wload(kt, 0, bh0, bl0);
        lds_barrier();
        #pragma unroll
        for (int rt = 0; rt < 8; ++rt) {
            const int row = rg * 128 + rt * 16 + l15;
            const half8 ah = *(const half8*)(smem + OFF_XH + swz128(row, kg * 8));
            const half8 al = *(const half8*)(smem + OFF_XL + swz128(row, kg * 8));
            #pragma unroll
            for (int ct = 0; ct < 3; ++ct) {
                acc[rt][ct] = __builtin_amdgcn_mfma_f32_16x16x32_f16(ah, bh0[ct], acc[rt][ct], 0, 0, 0);
                acc[rt][ct] = __builtin_amdgcn_mfma_f32_16x16x32_f16(ah, bl0[ct], acc[rt][ct], 0, 0, 0);
                acc[rt][ct] = __builtin_amdgcn_mfma_f32_16x16x32_f16(al, bh0[ct], acc[rt][ct], 0, 0, 0);
            }
        }
        half8 bh1[3], bl1[3];
        wload(kt, 1, bh1, bl1);
        #pragma unroll
        for (int rt = 0; rt < 8; ++rt) {
            const int row = rg * 128 + rt * 16 + l15;
            const half8 ah = *(const half8*)(smem + OFF_XH + swz128(row, 32 + kg * 8));
            const half8 al = *(const half8*)(smem + OFF_XL + swz128(row, 32 + kg * 8));
            #pragma unroll
            for (int ct = 0; ct < 3; ++ct) {
                acc[rt][ct] = __builtin_amdgcn_mfma_f32_16x16x32_f16(ah, bh1[ct], acc[rt][ct], 0, 0, 0);
                acc[rt][ct] = __builtin_amdgcn_mfma_f32_16x16x32_f16(ah, bl1[ct], acc[rt][ct], 0, 0, 0);
                acc[rt][ct] = __builtin_amdgcn_mfma_f32_16x16x32_f16(al, bh1[ct], acc[rt][ct], 0, 0, 0);
            }
        }
        lds_barrier();
    }

    // ---- epilogue: bias; K hi/lo + V^T -> LDS; Q extracted to qfrag ----
    float4a qfrag[8];
    {
        const int a = cg * 16 + l15;
        const float biq = bq[a], bik = bk[a], biv = bv[a];
        #pragma unroll
        for (int rt = 0; rt < 8; ++rt) {
            #pragma unroll
            for (int jj = 0; jj < 4; ++jj) {
                qfrag[rt][jj] = acc[rt][0][jj] + biq;
                const int m = rg * 128 + rt * 16 + kg * 4 + jj;
                const float kv = acc[rt][1][jj] + bik;
                const _Float16 kh = (_Float16)kv;
                *(_Float16*)(smem + OFF_KH + swz128(m, a)) = kh;
                *(_Float16*)(smem + OFF_KL + swz128(m, a)) = (_Float16)(kv - (float)kh);
            }
            const int m0 = rg * 128 + rt * 16 + kg * 4;
            half4 vh;
            #pragma unroll
            for (int jj = 0; jj < 4; ++jj)
                vh[jj] = (_Float16)(acc[rt][2][jj] + biv);
            *(half4*)(smem + OFF_VST + swz512(a, m0)) = vh;
        }
    }

    const int rt_s = w & 3;    // chunk-local row-tile
    const int mq   = w >> 2;   // S: m-half
    const int ah2  = w >> 2;   // PV: a-half
    const int cgf  = w >> 2;   // fc: col-half (cc cgf*128..+127)
    const float gv = gama[0];
    float fcbv[8];
    #pragma unroll
    for (int i = 0; i < 8; ++i) fcbv[i] = fcb[cgf * 128 + i * 16 + l15];
    float* red1 = (float*)(smem + OFF_RED1);
    float* red2 = (float*)(smem + OFF_RED2);
    lds_barrier();

    // ============ Phase B: attention + fc, 4 chunks of 64 rows ============
    #pragma unroll 1
    for (int ci = 0; ci < 4; ++ci) {
        // ---- 1. chunk's Q rows -> LDS (f16 hi/lo) ----
        if (rg == (ci >> 1)) {
            const int a = cg * 16 + l15;
            #pragma unroll
            for (int rt4 = 0; rt4 < 4; ++rt4) {
                const int rt = ((ci & 1) << 2) + rt4;
                #pragma unroll
                for (int jj = 0; jj < 4; ++jj) {
                    const int rloc = rt4 * 16 + kg * 4 + jj;
                    const float qv = qfrag[rt][jj];
                    const _Float16 qh = (_Float16)qv;
                    *(_Float16*)(smem + OFF_QTH + swz128(rloc, a)) = qh;
                    *(_Float16*)(smem + OFF_QTL + swz128(rloc, a)) = (_Float16)(qv - (float)qh);
                }
            }
        }
        lds_barrier();                                       // bar A

        // ---- 2. S = Q K^T (3-term split-f16 MFMA); wave: 16 rows x 128 m ----
        float4a sacc[8];
        #pragma unroll
        for (int mt = 0; mt < 8; ++mt) sacc[mt] = (float4a)0.0f;
        const int arow = rt_s * 16 + l15;
        #pragma unroll
        for (int ks = 0; ks < 2; ++ks) {
            const int a0 = ks * 32 + kg * 8;
            const half8 ah = *(const half8*)(smem + OFF_QTH + swz128(arow, a0));
            const half8 al = *(const half8*)(smem + OFF_QTL + swz128(arow, a0));
            #pragma unroll
            for (int mt = 0; mt < 8; ++mt) {
                const int mcol = mq * 128 + mt * 16 + l15;
                const half8 bh = *(const half8*)(smem + OFF_KH + swz128(mcol, a0));
                const half8 bl = *(const half8*)(smem + OFF_KL + swz128(mcol, a0));
                sacc[mt] = __builtin_amdgcn_mfma_f32_16x16x32_f16(ah, bh, sacc[mt], 0, 0, 0);
                sacc[mt] = __builtin_amdgcn_mfma_f32_16x16x32_f16(ah, bl, sacc[mt], 0, 0, 0);
                sacc[mt] = __builtin_amdgcn_mfma_f32_16x16x32_f16(al, bh, sacc[mt], 0, 0, 0);
            }
        }

        // ---- 3. softmax over m (merged reduction, [64][2] slots) ----
        float mloc[4];
        #pragma unroll
        for (int jj = 0; jj < 4; ++jj) {
            float m0 = sacc[0][jj];
            #pragma unroll
            for (int mt = 1; mt < 8; ++mt) m0 = fmaxf(m0, sacc[mt][jj]);
            m0 = fmaxf(m0, __shfl_xor(m0, 1));
            m0 = fmaxf(m0, __shfl_xor(m0, 2));
            m0 = fmaxf(m0, __shfl_xor(m0, 4));
            m0 = fmaxf(m0, __shfl_xor(m0, 8));
            mloc[jj] = m0;
        }
        #pragma unroll
        for (int mt = 0; mt < 8; ++mt)
            #pragma unroll
            for (int jj = 0; jj < 4; ++jj)
                sacc[mt][jj] = __expf(sacc[mt][jj] - mloc[jj]);
        #pragma unroll
        for (int jj = 0; jj < 4; ++jj) {
            float s0 = 0.0f;
            #pragma unroll
            for (int mt = 0; mt < 8; ++mt) s0 += sacc[mt][jj];
            s0 += __shfl_xor(s0, 1);
            s0 += __shfl_xor(s0, 2);
            s0 += __shfl_xor(s0, 4);
            s0 += __shfl_xor(s0, 8);
            if (l15 == 0) {
                const int rloc = rt_s * 16 + kg * 4 + jj;
                red1[rloc * 2 + mq] = mloc[jj];
                red2[rloc * 2 + mq] = s0;
            }
        }
        lds_barrier();                                       // bar B
        #pragma unroll
        for (int jj = 0; jj < 4; ++jj) {
            const int rloc = rt_s * 16 + kg * 4 + jj;
            const float rm0 = red1[rloc * 2], rm1 = red1[rloc * 2 + 1];
            const float rs0 = red2[rloc * 2], rs1 = red2[rloc * 2 + 1];
            const float gmax = fmaxf(rm0, rm1);
            const float total = rs0 * __expf(rm0 - gmax) + rs1 * __expf(rm1 - gmax);
            const float fac = __expf(mloc[jj] - gmax) / total;
            #pragma unroll
            for (int mt = 0; mt < 8; ++mt) {
                const int mcol = mq * 128 + mt * 16 + l15;
                *(_Float16*)(smem + OFF_PT + swz512(rloc, mcol)) =
                    (_Float16)(sacc[mt][jj] * fac);
            }
        }
        // issue scattered residual-Y loads now (global; in flight across bars,
        // consumed at the direct store after fc)
        float yv[8][4];
        #pragma unroll
        for (int i = 0; i < 8; ++i)
            #pragma unroll
            for (int jj = 0; jj < 4; ++jj) {
                const int row = ci * 64 + rt_s * 16 + kg * 4 + jj;
                const int col = cgf * 128 + i * 16 + l15;
                yv[i][jj] = Yb[(size_t)row * 16384 + col];
            }
        lds_barrier();                                       // bar C

        // ---- 4. PV = P * V (single f16 MFMA); wave: 16 rows x 32 a ----
        float4a pacc[2];
        pacc[0] = (float4a)0.0f; pacc[1] = (float4a)0.0f;
        #pragma unroll
        for (int ks = 0; ks < 8; ++ks) {
            const int mk = ks * 32 + kg * 8;
            const half8 pa = *(const half8*)(smem + OFF_PT + swz512(rt_s * 16 + l15, mk));
            #pragma unroll
            for (int i = 0; i < 2; ++i) {
                const half8 vb = *(const half8*)(smem + OFF_VST + swz512((ah2 * 2 + i) * 16 + l15, mk));
                pacc[i] = __builtin_amdgcn_mfma_f32_16x16x32_f16(pa, vb, pacc[i], 0, 0, 0);
            }
        }
        #pragma unroll
        for (int i = 0; i < 2; ++i)
            #pragma unroll
            for (int jj = 0; jj < 4; ++jj) {
                const int rloc = rt_s * 16 + kg * 4 + jj;
                const int colp = (ah2 * 2 + i) * 16 + l15;
                const float pv = pacc[i][jj];
                const _Float16 ph = (_Float16)pv;
                *(_Float16*)(smem + OFF_PVH + swz128(rloc, colp)) = ph;
                *(_Float16*)(smem + OFF_PVL + swz128(rloc, colp)) = (_Float16)(pv - (float)ph);
            }
        lds_barrier();                                       // bar D

        // ---- 5. fc via MFMA (3-term) + DIRECT gated-residual store ----
        float4a facc[8];
        #pragma unroll
        for (int i = 0; i < 8; ++i) facc[i] = (float4a)0.0f;
        #pragma unroll
        for (int ks = 0; ks < 2; ++ks) {
            const int aoff = ks * 32 + kg * 8;
            const half8 ah = *(const half8*)(smem + OFF_PVH + swz128(rt_s * 16 + l15, aoff));
            const half8 al = *(const half8*)(smem + OFF_PVL + swz128(rt_s * 16 + l15, aoff));
            #pragma unroll
            for (int i = 0; i < 8; ++i) {
                const int cc = cgf * 128 + i * 16 + l15;
                const half8 bfh = *(const half8*)(ws + WS_FC + cc * 64 + aoff);
                const half8 bfl = *(const half8*)(ws + WS_FC_LO + cc * 64 + aoff);
                facc[i] = __builtin_amdgcn_mfma_f32_16x16x32_f16(ah, bfh, facc[i], 0, 0, 0);
                facc[i] = __builtin_amdgcn_mfma_f32_16x16x32_f16(al, bfh, facc[i], 0, 0, 0);
                facc[i] = __builtin_amdgcn_mfma_f32_16x16x32_f16(ah, bfl, facc[i], 0, 0, 0);
            }
        }
        #pragma unroll
        for (int i = 0; i < 8; ++i)
            #pragma unroll
            for (int jj = 0; jj < 4; ++jj) {
                const int row = ci * 64 + rt_s * 16 + kg * 4 + jj;
                const int col = cgf * 128 + i * 16 + l15;
                Ob[(size_t)row * 16384 + col] =
                    yv[i][jj] + gv * (facc[i][jj] + fcbv[i]);
            }
        // no trailing barrier: next chunk's Q write targets QTH/QTL, whose
        // last readers (this chunk's S) all passed bar B; PT/PVH rewrites in
        // the next chunk are fenced by its own bars B/C/D.
    }
}

extern "C" void kernel_launch(void* const* d_in, const int* in_sizes, int n_in,
                              void* d_out, int out_size, void* d_ws, size_t ws_size,
                              hipStream_t stream) {
    (void)in_sizes; (void)n_in; (void)ws_size; (void)out_size;
    const float* Y    = (const float*)d_in[0];
    const float* Wq   = (const float*)d_in[1];
    const float* Wk   = (const float*)d_in[2];
    const float* Wv   = (const float*)d_in[3];
    const float* bq   = (const float*)d_in[4];
    const float* bk   = (const float*)d_in[5];
    const float* bv   = (const float*)d_in[6];
    const float* gama = (const float*)d_in[7];
    const float* fcw  = (const float*)d_in[8];
    const float* fcb  = (const float*)d_in[9];
    float* outp = (float*)d_out;
    _Float16* ws = (_Float16*)d_ws;

    (void)hipFuncSetAttribute((const void*)va_fused,
                              hipFuncAttributeMaxDynamicSharedMemorySize, LDS_BYTES);

    va_prep<<<dim3(193), dim3(256), 0, stream>>>(Wq, Wk, Wv, fcw, ws);
    va_fused<<<dim3(1024), dim3(512), LDS_BYTES, stream>>>(
        Y, bq, bk, bv, gama, fcb, ws, outp);
}